// Round 6
// baseline (171.376 us; speedup 1.0000x reference)
//
#include <hip/hip_runtime.h>
#include <hip/hip_bf16.h>

// GAT layer: B=4, N=2048, F=128, U=64, H=4.
//  k0: pack adj (64MB int32) -> bitmask (2MB)
//  k1: proj GEMM (vector fp32) -> pT_hi/pT_lo bf16 [h][b][u][n] (trunc-split
//      fp32: hi = high 16 bits, lo = bf16_rne(residual); hi+lo err ~2^-17),
//      transposed through LDS for coalesced stores; plus s[h][b][n] f32
//  k2: MFMA attention, JC=4 j-chunks, LDS-staged B (double-buffered
//      global_load_lds), w=adj?exp(si*sj):0 in-register trunc-split;
//      3-product split-bf16 MFMA. D layout per verified m89.
//      C-write bounced through LDS for contiguous float4 stores.
//  k3: combine: out = 0.25 * sum_h (sum_jc P) / (sum_jc Z)
//
// d_ws layout (bytes), total 44,695,552:
//   pT_hi    @ 0          : H*B*U*N bf16 = 4,194,304
//   pT_lo    @ 4,194,304  : H*B*U*N bf16 = 4,194,304
//   s        @ 8,388,608  : H*B*N   f32  =   131,072
//   adjbits  @ 8,519,680  : B*N*N/8      = 2,097,152
//   out_part @ 10,616,832 : H*JC*B*N*U f32 = 33,554,432
//   Z_part   @ 44,171,264 : H*JC*B*N f32 = 524,288

#define Bdim 4
#define Ndim 2048
#define Fdim 128
#define Udim 64
#define Hdim 4
#define JC 4
#define JCHUNK (Ndim / JC)  // 512

typedef __attribute__((ext_vector_type(8))) short short8;
typedef __attribute__((ext_vector_type(4))) float f32x4;

__device__ __forceinline__ short bf16_rne(float f) {
  union { __hip_bfloat16 b; unsigned short u; } c;
  c.b = __float2bfloat16(f);
  return (short)c.u;
}

// trunc split: hi = f's high 16 bits (exact bf16 by truncation, f>=0),
// lo = bf16_rne(f - float(hi)). hi+lo represents f to ~2^-17 rel.
__device__ __forceinline__ void splitbf(float f, short& hi, short& lo) {
  unsigned u = __float_as_uint(f);
  hi = (short)(u >> 16);
  float lof = f - __uint_as_float(u & 0xffff0000u);
  lo = bf16_rne(lof);
}

// async global->LDS, 16B per lane; dest = wave-uniform base + lane*16
__device__ __forceinline__ void stage16(const void* g, void* l) {
  __builtin_amdgcn_global_load_lds(
      (const __attribute__((address_space(1))) unsigned int*)g,
      (__attribute__((address_space(3))) unsigned int*)l, 16, 0, 0);
}

// ---------------- k0: pack adjacency to bitmask ----------------
__global__ __launch_bounds__(256) void pack_adj_kernel(
    const int* __restrict__ adj, unsigned long long* __restrict__ bits,
    int nchunks) {
  const int lane = threadIdx.x & 63;
  const int wid = (blockIdx.x * 256 + threadIdx.x) >> 6;
  const int nw = (gridDim.x * 256) >> 6;
  for (int c = wid * 4; c + 3 < nchunks; c += nw * 4) {
    int v0 = adj[(size_t)(c + 0) * 64 + lane];
    int v1 = adj[(size_t)(c + 1) * 64 + lane];
    int v2 = adj[(size_t)(c + 2) * 64 + lane];
    int v3 = adj[(size_t)(c + 3) * 64 + lane];
    unsigned long long m0 = __ballot(v0 != 0);
    unsigned long long m1 = __ballot(v1 != 0);
    unsigned long long m2 = __ballot(v2 != 0);
    unsigned long long m3 = __ballot(v3 != 0);
    if (lane == 0) {
      bits[c + 0] = m0;
      bits[c + 1] = m1;
      bits[c + 2] = m2;
      bits[c + 3] = m3;
    }
  }
}

// ---------------- k1: projection -> split-bf16 transposed + s ----------------
__global__ __launch_bounds__(256) void proj_kernel(
    const float* __restrict__ x, const float* __restrict__ W,
    const float* __restrict__ bias, const float* __restrict__ a_w,
    const float* __restrict__ a_b, unsigned short* __restrict__ pTh,
    unsigned short* __restrict__ pTl, float* __restrict__ s) {
  const int bid = blockIdx.x;
  const int nt = bid & 31;
  const int b = (bid >> 5) & 3;
  const int h = bid >> 7;
  const int n0 = nt * 64;

  __shared__ __align__(16) char smem[71168];
  float (*Wl)[Udim] = (float(*)[Udim])(smem);                  // 32768 B
  float (*xl)[Fdim + 4] = (float(*)[Fdim + 4])(smem + 32768);  // 33792 B
  float (*pt)[68] = (float(*)[68])(smem + 32768);              // alias xl
  float* bl = (float*)(smem + 66560);
  float* awl = (float*)(smem + 66816);
  float (*sred)[16] = (float(*)[16])(smem + 67072);            // 4096 B

  const int t = threadIdx.x;

  const float* Wg = W + (size_t)h * Fdim * Udim;
  for (int k = t; k < Fdim * Udim / 4; k += 256) {
    ((float4*)&Wl[0][0])[k] = ((const float4*)Wg)[k];
  }
  if (t < Udim) {
    bl[t] = bias[h * Udim + t];
    awl[t] = a_w[h * Udim + t];
  }
  const float* xg = x + ((size_t)b * Ndim + n0) * Fdim;
  for (int k = t; k < 64 * Fdim / 4; k += 256) {
    int row = k >> 5;
    int c4 = k & 31;
    float4 v = ((const float4*)xg)[(size_t)row * (Fdim / 4) + c4];
    *(float4*)&xl[row][c4 * 4] = v;
  }
  __syncthreads();

  const int ug = t & 15, rg = t >> 4;
  const int u0 = ug * 4, r0 = rg * 4;
  float acc[4][4] = {};

#pragma unroll 4
  for (int f = 0; f < Fdim; ++f) {
    const float4 wv = *(const float4*)&Wl[f][u0];
    const float xv[4] = {xl[r0][f], xl[r0 + 1][f], xl[r0 + 2][f], xl[r0 + 3][f]};
#pragma unroll
    for (int c = 0; c < 4; ++c) {
      acc[c][0] = fmaf(xv[c], wv.x, acc[c][0]);
      acc[c][1] = fmaf(xv[c], wv.y, acc[c][1]);
      acc[c][2] = fmaf(xv[c], wv.z, acc[c][2]);
      acc[c][3] = fmaf(xv[c], wv.w, acc[c][3]);
    }
  }

  float po[4][4];  // [c = n-offset][k = u-offset]
#pragma unroll
  for (int c = 0; c < 4; ++c)
#pragma unroll
    for (int k = 0; k < 4; ++k)
      po[c][k] = fmaxf(acc[c][k] + bl[u0 + k], 0.f);

#pragma unroll
  for (int c = 0; c < 4; ++c) {
    float sp = po[c][0] * awl[u0 + 0] + po[c][1] * awl[u0 + 1] +
               po[c][2] * awl[u0 + 2] + po[c][3] * awl[u0 + 3];
    sred[r0 + c][ug] = sp;
  }
  __syncthreads();  // all xl reads done; safe to overwrite via pt alias

#pragma unroll
  for (int k = 0; k < 4; ++k) {
    float4 v = {po[0][k], po[1][k], po[2][k], po[3][k]};
    *(float4*)&pt[u0 + k][r0] = v;
  }
  __syncthreads();

  const size_t hb = (size_t)h * Bdim + b;
  const int su = t >> 2;
  const int snl = (t & 3) * 16;
  float v[16];
#pragma unroll
  for (int j = 0; j < 4; ++j)
    *(float4*)&v[4 * j] = *(const float4*)&pt[su][snl + 4 * j];
  short hi[16], lo[16];
#pragma unroll
  for (int k = 0; k < 16; ++k) splitbf(v[k], hi[k], lo[k]);
  unsigned short* ph =
      pTh + hb * (size_t)(Udim * Ndim) + (size_t)su * Ndim + n0 + snl;
  unsigned short* pl =
      pTl + hb * (size_t)(Udim * Ndim) + (size_t)su * Ndim + n0 + snl;
  *(short8*)(ph + 0) = *(short8*)&hi[0];
  *(short8*)(ph + 8) = *(short8*)&hi[8];
  *(short8*)(pl + 0) = *(short8*)&lo[0];
  *(short8*)(pl + 8) = *(short8*)&lo[8];

  if (t < 64) {
    float sum = a_b[h];
#pragma unroll
    for (int k = 0; k < 16; ++k) sum += sred[t][k];
    s[hb * Ndim + n0 + t] = sum;
  }
}

// ---------------- k2: MFMA masked-softmax aggregation, LDS-staged B --------
// grid: 2048 blocks = (h:4, b:4, itile:32, jc:4), 256 threads (4 waves).
// LDS 22.5 KB -> 7 blocks/CU. Wave wv: i-rows [i0g+wv*16,+16), u-tile-stage m=wv.
__global__ __launch_bounds__(256, 7) void attn_mfma_kernel(
    const unsigned short* __restrict__ pTh,
    const unsigned short* __restrict__ pTl, const float* __restrict__ s,
    const unsigned int* __restrict__ abits, float* __restrict__ out_part,
    float* __restrict__ Z_part) {
  const int bid = blockIdx.x;
  const int jc = bid & 3;
  const int it = (bid >> 2) & 31;
  const int b = (bid >> 7) & 3;
  const int h = bid >> 9;
  const int i0g = it * 64;
  const int j0g = jc * JCHUNK;

  __shared__ float sj[JCHUNK];                   // 2 KB
  __shared__ unsigned int ab[64][16];            // 4 KB
  __shared__ __align__(16) short Bst[2][8][512]; // 16 KB

  const int t = threadIdx.x;
  const int wv = t >> 6;
  const int lane = t & 63;
  const int q = lane >> 4;
  const int li = lane & 15;
  const size_t hb = (size_t)h * Bdim + b;
  const float* sg = s + hb * Ndim;

  ((float2*)sj)[t] = ((const float2*)(sg + j0g))[t];  // 512 floats
  {
    const int row = t >> 2, w4 = (t & 3) * 4;
    *(uint4*)&ab[row][w4] = *(const uint4*)&abits[((size_t)b * Ndim + i0g +
                                                   row) * (Ndim / 32) +
                                                  (j0g >> 5) + w4];
  }
  const int irow = wv * 16 + li;

  const unsigned short* bsrc_h =
      pTh + hb * (size_t)(Udim * Ndim) + (size_t)(wv * 16 + li) * Ndim + j0g +
      q * 8;
  const unsigned short* bsrc_l =
      pTl + hb * (size_t)(Udim * Ndim) + (size_t)(wv * 16 + li) * Ndim + j0g +
      q * 8;

  stage16(bsrc_h, &Bst[0][wv * 2 + 0][0]);
  stage16(bsrc_l, &Bst[0][wv * 2 + 1][0]);

  f32x4 acc[4] = {};
  float zacc = 0.f;
  __syncthreads();  // drains vmcnt: sj, ab, staged B all visible

  const float si = sg[i0g + irow];
  int buf = 0;

  for (int js = 0; js < JCHUNK; js += 32) {
    if (js + 32 < JCHUNK) {
      stage16(bsrc_h + js + 32, &Bst[buf ^ 1][wv * 2 + 0][0]);
      stage16(bsrc_l + js + 32, &Bst[buf ^ 1][wv * 2 + 1][0]);
    }
    const short8 b0h = *(const short8*)&Bst[buf][0][lane * 8];
    const short8 b0l = *(const short8*)&Bst[buf][1][lane * 8];
    const short8 b1h = *(const short8*)&Bst[buf][2][lane * 8];
    const short8 b1l = *(const short8*)&Bst[buf][3][lane * 8];
    const short8 b2h = *(const short8*)&Bst[buf][4][lane * 8];
    const short8 b2l = *(const short8*)&Bst[buf][5][lane * 8];
    const short8 b3h = *(const short8*)&Bst[buf][6][lane * 8];
    const short8 b3l = *(const short8*)&Bst[buf][7][lane * 8];
    const unsigned int mb = (ab[irow][js >> 5] >> (q * 8)) & 0xffu;
    const f32x4 s0 = *(const f32x4*)&sj[js + q * 8];
    const f32x4 s1 = *(const f32x4*)&sj[js + q * 8 + 4];
    const float sv[8] = {s0.x, s0.y, s0.z, s0.w, s1.x, s1.y, s1.z, s1.w};
    short8 ahi, alo;
#pragma unroll
    for (int e = 0; e < 8; ++e) {
      float we = __expf(si * sv[e]);
      we = ((mb >> e) & 1u) ? we : 0.f;
      zacc += we;
      short hh, ll;
      splitbf(we, hh, ll);
      ahi[e] = hh;
      alo[e] = ll;
    }
    acc[0] = __builtin_amdgcn_mfma_f32_16x16x32_bf16(ahi, b0h, acc[0], 0, 0, 0);
    acc[1] = __builtin_amdgcn_mfma_f32_16x16x32_bf16(ahi, b1h, acc[1], 0, 0, 0);
    acc[2] = __builtin_amdgcn_mfma_f32_16x16x32_bf16(ahi, b2h, acc[2], 0, 0, 0);
    acc[3] = __builtin_amdgcn_mfma_f32_16x16x32_bf16(ahi, b3h, acc[3], 0, 0, 0);
    acc[0] = __builtin_amdgcn_mfma_f32_16x16x32_bf16(alo, b0h, acc[0], 0, 0, 0);
    acc[1] = __builtin_amdgcn_mfma_f32_16x16x32_bf16(alo, b1h, acc[1], 0, 0, 0);
    acc[2] = __builtin_amdgcn_mfma_f32_16x16x32_bf16(alo, b2h, acc[2], 0, 0, 0);
    acc[3] = __builtin_amdgcn_mfma_f32_16x16x32_bf16(alo, b3h, acc[3], 0, 0, 0);
    acc[0] = __builtin_amdgcn_mfma_f32_16x16x32_bf16(ahi, b0l, acc[0], 0, 0, 0);
    acc[1] = __builtin_amdgcn_mfma_f32_16x16x32_bf16(ahi, b1l, acc[1], 0, 0, 0);
    acc[2] = __builtin_amdgcn_mfma_f32_16x16x32_bf16(ahi, b2l, acc[2], 0, 0, 0);
    acc[3] = __builtin_amdgcn_mfma_f32_16x16x32_bf16(ahi, b3l, acc[3], 0, 0, 0);
    __syncthreads();
    buf ^= 1;
  }

  // Z: reduce across q (lanes li, li+16, li+32, li+48)
  zacc += __shfl_xor(zacc, 16, 64);
  zacc += __shfl_xor(zacc, 32, 64);
  const size_t pslab = ((size_t)h * JC + jc) * Bdim + b;
  if (q == 0) Z_part[pslab * Ndim + i0g + wv * 16 + li] = zacc;

  // C-write: bounce acc through LDS (Bst dead) for contiguous float4 stores
  float* cbuf = (float*)&Bst[0][0][0];  // 4096 f32; wave wv owns [wv*1024,+1024)
#pragma unroll
  for (int r = 0; r < 4; ++r)
#pragma unroll
    for (int m = 0; m < 4; ++m)
      cbuf[wv * 1024 + (q * 4 + r) * 64 + m * 16 + li] = acc[m][r];
  __syncthreads();
  {
    const int row = lane >> 2, c0 = (lane & 3) * 16;
    const float* src = &cbuf[wv * 1024 + row * 64 + c0];
    float* op =
        out_part + (pslab * Ndim + i0g + wv * 16 + row) * Udim + c0;
#pragma unroll
    for (int k = 0; k < 4; ++k)
      *(float4*)(op + k * 4) = *(const float4*)(src + k * 4);
  }
}

// ---------------- k3: combine partials, normalize, head-mean ----------------
__global__ __launch_bounds__(256) void combine_kernel(
    const float* __restrict__ out_part, const float* __restrict__ Z_part,
    float* __restrict__ out) {
  const int idx = blockIdx.x * 256 + threadIdx.x;
  const int u4 = idx & 15;
  const size_t bn = (size_t)(idx >> 4);
  float4 r = {0.f, 0.f, 0.f, 0.f};
#pragma unroll
  for (int h = 0; h < Hdim; ++h) {
    float4 p = {0.f, 0.f, 0.f, 0.f};
    float z = 0.f;
#pragma unroll
    for (int j = 0; j < JC; ++j) {
      const size_t sl = ((size_t)h * JC + j) * (Bdim * Ndim) + bn;
      float4 pj = ((const float4*)out_part)[sl * (Udim / 4) + u4];
      p.x += pj.x; p.y += pj.y; p.z += pj.z; p.w += pj.w;
      z += Z_part[sl];
    }
    z = (z != 0.f) ? z : 1.f;
    const float inv = 1.f / z;
    r.x += p.x * inv;
    r.y += p.y * inv;
    r.z += p.z * inv;
    r.w += p.w * inv;
  }
  r.x *= 0.25f; r.y *= 0.25f; r.z *= 0.25f; r.w *= 0.25f;
  ((float4*)out)[idx] = r;
}

extern "C" void kernel_launch(void* const* d_in, const int* in_sizes, int n_in,
                              void* d_out, int out_size, void* d_ws,
                              size_t ws_size, hipStream_t stream) {
  const float* x = (const float*)d_in[0];
  const int* adj = (const int*)d_in[1];
  const float* W = (const float*)d_in[2];
  const float* bias = (const float*)d_in[3];
  const float* a_w = (const float*)d_in[4];
  const float* a_b = (const float*)d_in[5];
  float* out = (float*)d_out;

  char* ws = (char*)d_ws;
  unsigned short* pTh = (unsigned short*)(ws + 0);
  unsigned short* pTl = (unsigned short*)(ws + 4194304);
  float* s = (float*)(ws + 8388608);
  unsigned int* adjbits = (unsigned int*)(ws + 8519680);
  float* out_part = (float*)(ws + 10616832);
  float* Z_part = (float*)(ws + 44171264);

  const int nchunks = Bdim * Ndim * Ndim / 64;  // 262144
  pack_adj_kernel<<<2048, 256, 0, stream>>>(adj, (unsigned long long*)adjbits,
                                            nchunks);
  proj_kernel<<<Hdim * Bdim * 32, 256, 0, stream>>>(x, W, bias, a_w, a_b, pTh,
                                                    pTl, s);
  attn_mfma_kernel<<<Hdim * Bdim * 32 * JC, 256, 0, stream>>>(
      pTh, pTl, s, adjbits, out_part, Z_part);
  combine_kernel<<<(Bdim * Ndim * Udim / 4) / 256, 256, 0, stream>>>(
      out_part, Z_part, out);
}